// Round 7
// baseline (439.732 us; speedup 1.0000x reference)
//
#include <hip/hip_runtime.h>

// Chamfer distance via 32x32x16 bf16 MFMA, N=M=16384, D=3, f32.
// min_j dist(p,q_j) = -2*( max_j (dot(p,q_j) - 0.5|q_j|^2) - 0.5|p|^2 ), >= 0.
// 2-way bf16 split per coord (hi+lo = 16 mantissa bits; dropped residual
// <= 2^-18|x| -> ~1e-5 per distance, ~1e-6 on the mean output): 4 cross
// products per dim occupy K-slots k = d*4 + a*2 + t (12 slots); slots 12,13
// carry the 2-split of -0.5|q|^2 against 1.0; 14,15 zero. One
// mfma_f32_32x32x16_bf16 = 32 q x 32 owners = 1024 pairs in ~8 cyc.
// R6 vs R5 (55us, VGPR=44 => operands thrashed through ACC regs): per-thread
// live state ~60 regs (b[4]=16, mx[4]=4, a=4, one 16-reg D transient), inner
// loop FULLY unrolled (compile-time LDS offsets, no rotation/stagger math).

typedef short bf16x8 __attribute__((ext_vector_type(8)));  // 8 bf16 = 4 VGPR
typedef float f32x16 __attribute__((ext_vector_type(16)));

#define NPTS   16384
#define TPB    256
#define OT     4                  // owner 32-tiles per wave -> 128 owners/wave
#define OPW    (OT * 32)          // 128
#define OPB    (OPW * 4)          // 512 owners per block (4 waves)
#define SLICES 32                 // q slices
#define QSL    (NPTS / SLICES)    // 512 q per slice -> 16 KB LDS
#define NT     (QSL / 32)         // 16 q-tiles per slice

__device__ __forceinline__ unsigned short f2b(float f) {  // fp32 -> bf16 RNE
    union { float f; unsigned u; } a; a.f = f;
    return (unsigned short)((a.u + 0x7FFFu + ((a.u >> 16) & 1u)) >> 16);
}
__device__ __forceinline__ float b2f(unsigned short b) {
    union { unsigned u; float f; } a; a.u = ((unsigned)b) << 16;
    return a.f;
}

// Per point, build the A-role (q-side) and B-role (owner-side) 16-slot bf16
// k-vectors, the fp32 0.5|v|^2, and init the min array (every call: graph
// replay must be deterministic).
__global__ __launch_bounds__(TPB) void cd_prep(
        const float* __restrict__ x, const float* __restrict__ y,
        unsigned short* __restrict__ xA, unsigned short* __restrict__ xB,
        unsigned short* __restrict__ yA, unsigned short* __restrict__ yB,
        float* __restrict__ xh, float* __restrict__ yh,
        unsigned* __restrict__ minx, unsigned* __restrict__ miny, int n, int m) {
    int i = blockIdx.x * TPB + threadIdx.x;
    if (i >= n + m) return;
    const float* src = (i < n) ? x : y;
    int k = (i < n) ? i : i - n;
    unsigned short* A = (i < n) ? xA : yA;
    unsigned short* B = (i < n) ? xB : yB;
    float* h = (i < n) ? xh : yh;
    unsigned* mn = (i < n) ? minx : miny;

    float v[3] = { src[3 * k], src[3 * k + 1], src[3 * k + 2] };
    unsigned short sp[3][2];  // [dim][split: hi, lo]
#pragma unroll
    for (int d = 0; d < 3; ++d) {
        sp[d][0] = f2b(v[d]);
        sp[d][1] = f2b(v[d] - b2f(sp[d][0]));
    }
    float half = 0.5f * (v[0] * v[0] + v[1] * v[1] + v[2] * v[2]);
    unsigned short ss[2];
    ss[0] = f2b(-half);
    ss[1] = f2b(-half - b2f(ss[0]));

    unsigned short Av[16], Bv[16];
#pragma unroll
    for (int d = 0; d < 3; ++d)
#pragma unroll
        for (int a = 0; a < 2; ++a)        // owner-split index
#pragma unroll
            for (int t = 0; t < 2; ++t) {  // q-split index
                Av[d * 4 + a * 2 + t] = sp[d][t];  // q side
                Bv[d * 4 + a * 2 + t] = sp[d][a];  // owner side
            }
    Av[12] = ss[0]; Av[13] = ss[1]; Bv[12] = 0x3F80; Bv[13] = 0x3F80;  // 1.0
    Av[14] = 0; Av[15] = 0; Bv[14] = 0; Bv[15] = 0;

    unsigned* Ao = (unsigned*)(A + (size_t)k * 16);
    unsigned* Bo = (unsigned*)(B + (size_t)k * 16);
#pragma unroll
    for (int j = 0; j < 8; ++j) {
        Ao[j] = (unsigned)Av[2 * j] | ((unsigned)Av[2 * j + 1] << 16);
        Bo[j] = (unsigned)Bv[2 * j] | ((unsigned)Bv[2 * j + 1] << 16);
    }
    h[k] = half;
    mn[k] = 0x7f800000u;  // +inf
}

// blockIdx = (owner-block, q-slice, direction). Block stages its 512-q
// A-slice in LDS (linear, 32 B/row: reads are 2-way bank-aliased = free).
// Each wave: 128 resident owners (4 B-frags) x 16 q-tiles; per tile
// 1 ds_read_b128 + 4 MFMA + 32 v_max3. Fragment layout (32x32x16):
// point = lane&31, k = (lane>>5)*8 + e for A and B; C/D col = lane&31,
// rows spread over lane>>5 halves -> epilogue shfl_xor(32).
// Slice partials via uint atomicMin (distances >= 0).
__global__ __launch_bounds__(TPB, 2) void cd_pass(
        const unsigned short* __restrict__ xA, const unsigned short* __restrict__ xB,
        const unsigned short* __restrict__ yA, const unsigned short* __restrict__ yB,
        const float* __restrict__ xh, const float* __restrict__ yh,
        unsigned* __restrict__ minx, unsigned* __restrict__ miny) {
    __shared__ __align__(16) char As[QSL * 32];

    const int lane = threadIdx.x & 63;
    const int wave = threadIdx.x >> 6;
    const int r = lane & 31, g = lane >> 5;

    const unsigned short* Aq; const unsigned short* Bp;
    const float* hs; unsigned* out;
    if (blockIdx.z == 0) { Aq = yA; Bp = xB; hs = xh; out = minx; }  // owners=x
    else                 { Aq = xA; Bp = yB; hs = yh; out = miny; }  // owners=y

    // Stage A slice -> LDS linear. 1024 16B-chunks, 256 threads, 4 iters.
    const int q0 = blockIdx.y * QSL;
    const float4* srcA = (const float4*)(Aq + (size_t)q0 * 16);
#pragma unroll
    for (int it = 0; it < (QSL * 2) / TPB; ++it) {
        int idx = it * TPB + threadIdx.x;
        ((float4*)As)[idx] = srcA[idx];
    }
    __syncthreads();

    const int obase = blockIdx.x * OPB + wave * OPW;
    bf16x8 b[OT];
    float mx[OT];
#pragma unroll
    for (int o = 0; o < OT; ++o) {
        b[o] = *(const bf16x8*)(Bp + (size_t)(obase + o * 32 + r) * 16 + g * 8);
        mx[o] = -INFINITY;
    }

    const int lbase = r * 32 + g * 16;  // per-lane LDS base within a tile
    const f32x16 zero = {0.f, 0.f, 0.f, 0.f, 0.f, 0.f, 0.f, 0.f,
                         0.f, 0.f, 0.f, 0.f, 0.f, 0.f, 0.f, 0.f};
#pragma unroll
    for (int t = 0; t < NT; ++t) {
        bf16x8 a = *(const bf16x8*)(As + lbase + t * 1024);
#pragma unroll
        for (int o = 0; o < OT; ++o) {
            f32x16 d = __builtin_amdgcn_mfma_f32_32x32x16_bf16(a, b[o], zero, 0, 0, 0);
            float m0 = mx[o];
            m0 = fmaxf(m0, fmaxf(d[0], d[1]));    // -> v_max3 chain (8)
            m0 = fmaxf(m0, fmaxf(d[2], d[3]));
            m0 = fmaxf(m0, fmaxf(d[4], d[5]));
            m0 = fmaxf(m0, fmaxf(d[6], d[7]));
            m0 = fmaxf(m0, fmaxf(d[8], d[9]));
            m0 = fmaxf(m0, fmaxf(d[10], d[11]));
            m0 = fmaxf(m0, fmaxf(d[12], d[13]));
            m0 = fmaxf(m0, fmaxf(d[14], d[15]));
            mx[o] = m0;
        }
    }

#pragma unroll
    for (int o = 0; o < OT; ++o) {
        float vv = fmaxf(mx[o], __shfl_xor(mx[o], 32, 64));
        if (lane < 32) {
            int id = obase + o * 32 + lane;
            float dmin = fmaxf(0.0f, 2.0f * (hs[id] - vv));
            atomicMin(&out[id], __float_as_uint(dmin));
        }
    }
}

// Single-block final reduction: mean of minx[N] ++ miny[M].
__global__ __launch_bounds__(1024) void cd_reduce(const uint4* __restrict__ minx,
                                                  const uint4* __restrict__ miny,
                                                  float* __restrict__ out, int n, int mm) {
    float s = 0.0f;
    for (int i = threadIdx.x; i < n / 4; i += 1024) {
        uint4 v = minx[i];
        s += __uint_as_float(v.x) + __uint_as_float(v.y) +
             __uint_as_float(v.z) + __uint_as_float(v.w);
    }
    for (int i = threadIdx.x; i < mm / 4; i += 1024) {
        uint4 v = miny[i];
        s += __uint_as_float(v.x) + __uint_as_float(v.y) +
             __uint_as_float(v.z) + __uint_as_float(v.w);
    }
    for (int off = 32; off >= 1; off >>= 1) s += __shfl_down(s, off, 64);
    __shared__ float wsum[16];
    int wave = threadIdx.x >> 6;
    int lane = threadIdx.x & 63;
    if (lane == 0) wsum[wave] = s;
    __syncthreads();
    if (threadIdx.x == 0) {
        float t = 0.0f;
        for (int w = 0; w < 16; ++w) t += wsum[w];
        out[0] = t / (float)(n + mm);
    }
}

extern "C" void kernel_launch(void* const* d_in, const int* in_sizes, int n_in,
                              void* d_out, int out_size, void* d_ws, size_t ws_size,
                              hipStream_t stream) {
    const float* x = (const float*)d_in[0];
    const float* y = (const float*)d_in[1];
    const int N = in_sizes[0] / 3;  // 16384
    const int M = in_sizes[1] / 3;  // 16384

    unsigned short* xA = (unsigned short*)d_ws;     // N*16 bf16
    unsigned short* xB = xA + (size_t)N * 16;       // N*16
    unsigned short* yA = xB + (size_t)N * 16;       // M*16
    unsigned short* yB = yA + (size_t)M * 16;       // M*16
    float* xh = (float*)(yB + (size_t)M * 16);      // N f32
    float* yh = xh + N;                             // M f32
    unsigned* minx = (unsigned*)(yh + M);           // N uint
    unsigned* miny = minx + N;                      // M uint
    float* out = (float*)d_out;

    cd_prep<<<(N + M + TPB - 1) / TPB, TPB, 0, stream>>>(x, y, xA, xB, yA, yB,
                                                         xh, yh, minx, miny, N, M);

    // grid: (owner blocks, q slices, direction) = (32, 32, 2) = 2048 blocks
    cd_pass<<<dim3(NPTS / OPB, SLICES, 2), TPB, 0, stream>>>(xA, xB, yA, yB,
                                                             xh, yh, minx, miny);

    cd_reduce<<<1, 1024, 0, stream>>>((const uint4*)minx, (const uint4*)miny, out, N, M);
}

// Round 8
// 56.824 us; speedup vs baseline: 7.7385x; 7.7385x over previous
//
#include <hip/hip_runtime.h>

// Chamfer distance via MFMA, N=M=16384, D=3, f32.
// min_j dist(p,q_j) = -2*( max_j (dot(p,q_j) - 0.5|q_j|^2) - 0.5|p|^2 ), >= 0.
// dot EXACT (to fp32 rounding) on the bf16 pipe: 3-way split per coord
// (hi/mid/lo = 24 mantissa bits), 9 cross products per dim in K-slots (27),
// slots 27..29 carry -0.5|q|^2 against 1.0. One mfma_f32_16x16x32_bf16 =
// 16 q x 16 owners of (dot - 0.5|q|^2).
// R7 vs R6 (spill disaster, VGPR=128, 1.7GB scratch traffic/dispatch):
// MINIMAL register footprint + MAX occupancy; no batching, no full unroll.
//  - OT=2 (b[2]=8 VGPR), one f32x4 D transient, consumed immediately
//    (sequential mx dependence prevents MFMA hoisting)
//  - TPB=1024: 16 waves/block, 2 blocks/CU -> 8 waves/SIMD; TLP hides MFMA
//    and LDS latency (m114: MFMA/VALU pipes co-schedule across waves)
//  - single LDS base reg; all 32 tile reads are offset: immediates

typedef short bf16x8 __attribute__((ext_vector_type(8)));  // 8 bf16 = 4 VGPR
typedef float f32x4 __attribute__((ext_vector_type(4)));

#define NPTS   16384
#define TPB    1024
#define OT     2                  // owner 16-tiles per wave -> 32 owners/wave
#define OPW    (OT * 16)          // 32
#define WVB    (TPB / 64)         // 16 waves per block
#define OPB    (OPW * WVB)        // 512 owners per block
#define SLICES 32                 // q slices
#define QSL    (NPTS / SLICES)    // 512 q per slice (32 KB LDS)
#define NT     (QSL / 16)         // 32 A-tiles per slice

__device__ __forceinline__ unsigned short f2b(float f) {  // fp32 -> bf16 RNE
    union { float f; unsigned u; } a; a.f = f;
    return (unsigned short)((a.u + 0x7FFFu + ((a.u >> 16) & 1u)) >> 16);
}
__device__ __forceinline__ float b2f(unsigned short b) {
    union { unsigned u; float f; } a; a.u = ((unsigned)b) << 16;
    return a.f;
}

// Per point, build the A-role (q-side) and B-role (owner-side) 32-slot bf16
// k-vectors, the fp32 0.5|v|^2, and init the min array (every call: graph
// replay must be deterministic).
__global__ __launch_bounds__(256) void cd_prep(
        const float* __restrict__ x, const float* __restrict__ y,
        unsigned short* __restrict__ xA, unsigned short* __restrict__ xB,
        unsigned short* __restrict__ yA, unsigned short* __restrict__ yB,
        float* __restrict__ xh, float* __restrict__ yh,
        unsigned* __restrict__ minx, unsigned* __restrict__ miny, int n, int m) {
    int i = blockIdx.x * 256 + threadIdx.x;
    if (i >= n + m) return;
    const float* src = (i < n) ? x : y;
    int k = (i < n) ? i : i - n;
    unsigned short* A = (i < n) ? xA : yA;
    unsigned short* B = (i < n) ? xB : yB;
    float* h = (i < n) ? xh : yh;
    unsigned* mn = (i < n) ? minx : miny;

    float v[3] = { src[3 * k], src[3 * k + 1], src[3 * k + 2] };
    unsigned short sp[3][3];  // [dim][split]
#pragma unroll
    for (int d = 0; d < 3; ++d) {
        float r = v[d];
        sp[d][0] = f2b(r); r -= b2f(sp[d][0]);
        sp[d][1] = f2b(r); r -= b2f(sp[d][1]);
        sp[d][2] = f2b(r);
    }
    float half = 0.5f * (v[0] * v[0] + v[1] * v[1] + v[2] * v[2]);
    unsigned short ss[3];
    { float r = -half;
      ss[0] = f2b(r); r -= b2f(ss[0]);
      ss[1] = f2b(r); r -= b2f(ss[1]);
      ss[2] = f2b(r); }

    unsigned short Av[32], Bv[32];
#pragma unroll
    for (int j = 0; j < 32; ++j) { Av[j] = 0; Bv[j] = 0; }
#pragma unroll
    for (int d = 0; d < 3; ++d)
#pragma unroll
        for (int a = 0; a < 3; ++a)        // owner-split index
#pragma unroll
            for (int t = 0; t < 3; ++t) {  // q-split index
                Av[d * 9 + a * 3 + t] = sp[d][t];  // q side: repeat over a
                Bv[d * 9 + a * 3 + t] = sp[d][a];  // p side: repeat over t
            }
#pragma unroll
    for (int a = 0; a < 3; ++a) { Av[27 + a] = ss[a]; Bv[27 + a] = 0x3F80; }  // 1.0

    unsigned* Ao = (unsigned*)(A + (size_t)k * 32);
    unsigned* Bo = (unsigned*)(B + (size_t)k * 32);
#pragma unroll
    for (int j = 0; j < 16; ++j) {
        Ao[j] = (unsigned)Av[2 * j] | ((unsigned)Av[2 * j + 1] << 16);
        Bo[j] = (unsigned)Bv[2 * j] | ((unsigned)Bv[2 * j + 1] << 16);
    }
    h[k] = half;
    mn[k] = 0x7f800000u;  // +inf
}

// blockIdx = (owner-block, q-slice, direction). Block stages its 512-q
// A-slice into LDS (XOR-swizzled, conflict-free for both float4 writes and
// b128 reads). Each of 16 waves: 32 resident owners (2 B-frags = 8 VGPR) x
// 32 A-tiles; per tile 1 ds_read_b128 + 2 MFMA + 4 v_max3, D consumed
// immediately. Slice partials via uint atomicMin (distances >= 0: float
// order == uint bit order).
__global__ __launch_bounds__(TPB) void cd_pass(
        const unsigned short* __restrict__ xA, const unsigned short* __restrict__ xB,
        const unsigned short* __restrict__ yA, const unsigned short* __restrict__ yB,
        const float* __restrict__ xh, const float* __restrict__ yh,
        unsigned* __restrict__ minx, unsigned* __restrict__ miny) {
    __shared__ __align__(16) char As[QSL * 64];

    const int lane = threadIdx.x & 63;
    const int wave = threadIdx.x >> 6;
    const int r = lane & 15, g = lane >> 4;

    const unsigned short* Aq; const unsigned short* Bp;
    const float* hs; unsigned* out;
    if (blockIdx.z == 0) { Aq = yA; Bp = xB; hs = xh; out = minx; }  // owners=x
    else                 { Aq = xA; Bp = yB; hs = yh; out = miny; }  // owners=y

    // Stage A slice -> LDS (swizzled). 2048 16B-chunks, 1024 threads, 2 iters.
    const int q0 = blockIdx.y * QSL;
#pragma unroll
    for (int it = 0; it < (QSL * 4) / TPB; ++it) {
        int idx = it * TPB + threadIdx.x;
        int row = idx >> 2, gg = idx & 3;
        float4 v = *(const float4*)(Aq + (size_t)(q0 + row) * 32 + gg * 8);
        *(float4*)(As + ((row * 64 + gg * 16) ^ ((row & 7) << 4))) = v;
    }
    __syncthreads();

    const int obase = blockIdx.x * OPB + wave * OPW;
    bf16x8 b0 = *(const bf16x8*)(Bp + (size_t)(obase + r) * 32 + g * 8);
    bf16x8 b1 = *(const bf16x8*)(Bp + (size_t)(obase + 16 + r) * 32 + g * 8);
    float mx0 = -INFINITY, mx1 = -INFINITY;

    // Per-lane LDS base: row = t*16 + r -> addr = lbase + t*1024 (immediates).
    const char* lp = As + ((r * 64 + g * 16) ^ ((r & 7) << 4));
    const f32x4 zero = {0.f, 0.f, 0.f, 0.f};
#pragma unroll 8
    for (int t = 0; t < NT; ++t) {
        bf16x8 a = *(const bf16x8*)(lp + t * 1024);
        f32x4 d = __builtin_amdgcn_mfma_f32_16x16x32_bf16(a, b0, zero, 0, 0, 0);
        mx0 = fmaxf(mx0, fmaxf(d[0], d[1]));  // -> v_max3
        mx0 = fmaxf(mx0, fmaxf(d[2], d[3]));
        f32x4 e = __builtin_amdgcn_mfma_f32_16x16x32_bf16(a, b1, zero, 0, 0, 0);
        mx1 = fmaxf(mx1, fmaxf(e[0], e[1]));
        mx1 = fmaxf(mx1, fmaxf(e[2], e[3]));
    }

    mx0 = fmaxf(mx0, __shfl_xor(mx0, 16, 64));
    mx0 = fmaxf(mx0, __shfl_xor(mx0, 32, 64));
    mx1 = fmaxf(mx1, __shfl_xor(mx1, 16, 64));
    mx1 = fmaxf(mx1, __shfl_xor(mx1, 32, 64));
    if (lane < 16) {
        int id0 = obase + lane;
        float d0 = fmaxf(0.0f, 2.0f * (hs[id0] - mx0));
        atomicMin(&out[id0], __float_as_uint(d0));
        int id1 = obase + 16 + lane;
        float d1 = fmaxf(0.0f, 2.0f * (hs[id1] - mx1));
        atomicMin(&out[id1], __float_as_uint(d1));
    }
}

// Single-block final reduction: mean of minx[N] ++ miny[M].
__global__ __launch_bounds__(1024) void cd_reduce(const uint4* __restrict__ minx,
                                                  const uint4* __restrict__ miny,
                                                  float* __restrict__ out, int n, int mm) {
    float s = 0.0f;
    for (int i = threadIdx.x; i < n / 4; i += 1024) {
        uint4 v = minx[i];
        s += __uint_as_float(v.x) + __uint_as_float(v.y) +
             __uint_as_float(v.z) + __uint_as_float(v.w);
    }
    for (int i = threadIdx.x; i < mm / 4; i += 1024) {
        uint4 v = miny[i];
        s += __uint_as_float(v.x) + __uint_as_float(v.y) +
             __uint_as_float(v.z) + __uint_as_float(v.w);
    }
    for (int off = 32; off >= 1; off >>= 1) s += __shfl_down(s, off, 64);
    __shared__ float wsum[16];
    int wave = threadIdx.x >> 6;
    int lane = threadIdx.x & 63;
    if (lane == 0) wsum[wave] = s;
    __syncthreads();
    if (threadIdx.x == 0) {
        float t = 0.0f;
        for (int w = 0; w < 16; ++w) t += wsum[w];
        out[0] = t / (float)(n + mm);
    }
}

extern "C" void kernel_launch(void* const* d_in, const int* in_sizes, int n_in,
                              void* d_out, int out_size, void* d_ws, size_t ws_size,
                              hipStream_t stream) {
    const float* x = (const float*)d_in[0];
    const float* y = (const float*)d_in[1];
    const int N = in_sizes[0] / 3;  // 16384
    const int M = in_sizes[1] / 3;  // 16384

    unsigned short* xA = (unsigned short*)d_ws;     // N*32 bf16
    unsigned short* xB = xA + (size_t)N * 32;       // N*32
    unsigned short* yA = xB + (size_t)N * 32;       // M*32
    unsigned short* yB = yA + (size_t)M * 32;       // M*32
    float* xh = (float*)(yB + (size_t)M * 32);      // N f32
    float* yh = xh + N;                             // M f32
    unsigned* minx = (unsigned*)(yh + M);           // N uint
    unsigned* miny = minx + N;                      // M uint
    float* out = (float*)d_out;

    cd_prep<<<(N + M + 255) / 256, 256, 0, stream>>>(x, y, xA, xB, yA, yB,
                                                     xh, yh, minx, miny, N, M);

    // grid: (owner blocks, q slices, direction) = (32, 32, 2) = 2048 blocks
    cd_pass<<<dim3(NPTS / OPB, SLICES, 2), TPB, 0, stream>>>(xA, xB, yA, yB,
                                                             xh, yh, minx, miny);

    cd_reduce<<<1, 1024, 0, stream>>>((const uint4*)minx, (const uint4*)miny, out, N, M);
}